// Round 11
// baseline (94.946 us; speedup 1.0000x reference)
//
#include <hip/hip_runtime.h>

// ---------------------------------------------------------------------------
// MixModel, 3 thread-segments/row, LDS-staged u-tiles, 2 tiles per block.
// Ladder: R1 136VGPR 127us | R2-R4 spill ~157 | R6 scalar 60VGPR 76us
//   R7 pk-f32 36VGPR 74.8us | R8 2rows/thr 85us (VGPR 64) | R9 gridstride
//   94.8us (VGPR 68) | R10 LDS-DMA 1 tile 71.1us (VGPR40, occ 57%, VALU 51%)
// R11: stage TWO 64-row tiles per 192-thr block (12 DMA insts total, issued
//   back-to-back so both tiles' HBM latencies overlap), ONE syncthreads
//   drain, then compute tile A then tile B stall-free. Stall fraction per
//   block ~44% -> ~29%; block count halves. Regs: tiles computed
//   sequentially, window regs reused (~48 VGPR). LDS 18.6KB -> 8 blocks/CU.
// Spill signature: WRITE_SIZE >> 140,625 KB.
// ---------------------------------------------------------------------------

typedef float f2 __attribute__((ext_vector_type(2)));

__device__ __forceinline__ f2 splat2(float x) { f2 v; v.x = x; v.y = x; return v; }
__device__ __forceinline__ f2 mk2(float a, float b) { f2 v; v.x = a; v.y = b; return v; }
__device__ __forceinline__ f2 fma2(f2 a, f2 b, f2 c) { return __builtin_elementwise_fma(a, b, c); }
__device__ __forceinline__ f2 relu2(f2 a) { return __builtin_elementwise_max(a, splat2(0.0f)); }

// Packed MLP 3->3->6->3 for a pair of positions.
__device__ __forceinline__ void mlp_a2(f2 x0, f2 x1, f2 x2,
                                       const float* __restrict__ w0, const float* __restrict__ b0,
                                       const float* __restrict__ w1, const float* __restrict__ b1,
                                       const float* __restrict__ w2, const float* __restrict__ b2,
                                       f2& o0, f2& o1, f2& o2)
{
    f2 h0[3];
#pragma unroll
    for (int q = 0; q < 3; ++q) {
        f2 a = fma2(x0, splat2(w0[q*3+0]), splat2(b0[q]));
        a = fma2(x1, splat2(w0[q*3+1]), a);
        a = fma2(x2, splat2(w0[q*3+2]), a);
        h0[q] = relu2(a);
    }
    f2 h1[6];
#pragma unroll
    for (int q = 0; q < 6; ++q) {
        f2 a = fma2(h0[0], splat2(w1[q*3+0]), splat2(b1[q]));
        a = fma2(h0[1], splat2(w1[q*3+1]), a);
        a = fma2(h0[2], splat2(w1[q*3+2]), a);
        h1[q] = relu2(a);
    }
    f2 t[3];
#pragma unroll
    for (int q = 0; q < 3; ++q) {
        f2 a = fma2(h1[0], splat2(w2[q*6+0]), splat2(b2[q]));
#pragma unroll
        for (int i = 1; i < 6; ++i) a = fma2(h1[i], splat2(w2[q*6+i]), a);
        t[q] = a;
    }
    o0 = t[0]; o1 = t[1]; o2 = t[2];
}

// Packed MLP 4->4->6->2 for a pair of positions.
__device__ __forceinline__ void mlp_b2(f2 x0, f2 x1, f2 x2, f2 x3,
                                       const float* __restrict__ w0, const float* __restrict__ b0,
                                       const float* __restrict__ w1, const float* __restrict__ b1,
                                       const float* __restrict__ w2, const float* __restrict__ b2,
                                       f2& o0, f2& o1)
{
    f2 h0[4];
#pragma unroll
    for (int q = 0; q < 4; ++q) {
        f2 a = fma2(x0, splat2(w0[q*4+0]), splat2(b0[q]));
        a = fma2(x1, splat2(w0[q*4+1]), a);
        a = fma2(x2, splat2(w0[q*4+2]), a);
        a = fma2(x3, splat2(w0[q*4+3]), a);
        h0[q] = relu2(a);
    }
    f2 h1[6];
#pragma unroll
    for (int q = 0; q < 6; ++q) {
        f2 a = fma2(h0[0], splat2(w1[q*4+0]), splat2(b1[q]));
        a = fma2(h0[1], splat2(w1[q*4+1]), a);
        a = fma2(h0[2], splat2(w1[q*4+2]), a);
        a = fma2(h0[3], splat2(w1[q*4+3]), a);
        h1[q] = relu2(a);
    }
    f2 t[2];
#pragma unroll
    for (int q = 0; q < 2; ++q) {
        f2 a = fma2(h1[0], splat2(w2[q*6+0]), splat2(b2[q]));
#pragma unroll
        for (int i = 1; i < 6; ++i) a = fma2(h1[i], splat2(w2[q*6+i]), a);
        t[q] = a;
    }
    o0 = t[0]; o1 = t[1];
}

// One (row-in-tile, r) segment: read 20-col window from LDS tile, compute,
// store 12 cols to global.
__device__ __forceinline__ void seg_compute(
    const float4* __restrict__ s4t, const float* __restrict__ sreg,
    int rl, int r,
    const float* __restrict__ w10, const float* __restrict__ b10,
    const float* __restrict__ w11, const float* __restrict__ b11,
    const float* __restrict__ w12, const float* __restrict__ b12,
    const float* __restrict__ w20, const float* __restrict__ b20,
    const float* __restrict__ w21, const float* __restrict__ b21,
    const float* __restrict__ w22, const float* __restrict__ b22,
    const float* __restrict__ w30, const float* __restrict__ b30,
    const float* __restrict__ w31, const float* __restrict__ b31,
    const float* __restrict__ w32, const float* __restrict__ b32,
    float4* __restrict__ o4)
{
    // ---- 20-col window: W(k) = u[row, (12r+k) mod 36], k=-4..15 ----
    float w_[20];
#pragma unroll
    for (int t = 0; t < 5; ++t) {
        int idx = 3 * r + 8 + t;               // 8..18
        if (idx >= 9) idx -= 9;                // 0..9
        if (idx >= 9) idx -= 9;                // 0..8 (double wrap)
        const float4 v = s4t[rl * 9 + idx];
        w_[4*t+0] = v.x; w_[4*t+1] = v.y; w_[4*t+2] = v.z; w_[4*t+3] = v.w;
    }
#define W(k) w_[(k) + 4]

    const f2 r02 = splat2(sreg[0]);
    const float* rb = sreg + 12 * r;

    f2 c0[2], c1[2], c2[2];   // pair P covers jj = 2P, 2P+1

#pragma unroll
    for (int P = 0; P < 2; ++P) {
        const int q = 6 * P;
        f2 a0, a1, a2;
        mlp_a2(mk2(W(q - 2), W(q + 1)), mk2(W(q), W(q + 3)), mk2(W(q + 1), W(q + 4)),
               w10, b10, w11, b11, w12, b12, a0, a1, a2);
        const f2 ua = mk2(W(q - 1), W(q + 2));
        const f2 ub = mk2(W(q + 2), W(q + 5));
        const f2 rv = mk2(rb[q + 1], rb[q + 4]);
        const f2 uv = mk2(W(q), W(q + 3));
        c0[P] = fma2(uv, rv, r02) + fma2(a2, ub, fma2(a1, ua, a0));
    }
#pragma unroll
    for (int P = 0; P < 2; ++P) {
        const int q = 6 * P;
        f2 a0, a1, a2;
        mlp_a2(mk2(W(q), W(q + 3)), mk2(W(q + 1), W(q + 4)), mk2(W(q + 3), W(q + 6)),
               w20, b20, w21, b21, w22, b22, a0, a1, a2);
        const f2 ua = mk2(W(q - 1), W(q + 2));
        const f2 ub = mk2(W(q + 2), W(q + 5));
        const f2 rv = mk2(rb[q + 2], rb[q + 5]);
        const f2 uv = mk2(W(q + 1), W(q + 4));
        c1[P] = fma2(uv, rv, r02) + fma2(a2, ub, fma2(a1, ua, a0));
    }
#pragma unroll
    for (int P = 0; P < 2; ++P) {
        const int q = 6 * P;
        f2 d0, d1;
        mlp_b2(mk2(W(q), W(q + 3)), mk2(W(q + 1), W(q + 4)),
               mk2(W(q + 3), W(q + 6)), mk2(W(q + 4), W(q + 7)),
               w30, b30, w31, b31, w32, b32, d0, d1);
        const f2 ub = mk2(W(q + 2), W(q + 5));
        const f2 rv = mk2(rb[q + 3], rb[q + 6]);
        c2[P] = fma2(ub, rv, r02) + fma2(d1, ub, d0);
    }
#undef W

    o4[0] = make_float4(c0[0].x, c1[0].x, c2[0].x, c0[0].y);
    o4[1] = make_float4(c1[0].y, c2[0].y, c0[1].x, c1[1].x);
    o4[2] = make_float4(c2[1].x, c0[1].y, c1[1].y, c2[1].y);
}

#define ROWS_PT 64        // rows per tile (576 float4)
#define TILES 2
#define TPB 192           // 3 waves; 576 f4 = 3 waves x 3 insts x 64 lanes

__global__ __launch_bounds__(TPB) void mixmodel_kernel(
    const float* __restrict__ u, const float* __restrict__ reg,
    const float* __restrict__ w10, const float* __restrict__ b10,
    const float* __restrict__ w11, const float* __restrict__ b11,
    const float* __restrict__ w12, const float* __restrict__ b12,
    const float* __restrict__ w20, const float* __restrict__ b20,
    const float* __restrict__ w21, const float* __restrict__ b21,
    const float* __restrict__ w22, const float* __restrict__ b22,
    const float* __restrict__ w30, const float* __restrict__ b30,
    const float* __restrict__ w31, const float* __restrict__ b31,
    const float* __restrict__ w32, const float* __restrict__ b32,
    float* __restrict__ out, int n)
{
    __shared__ float4 s4[TILES * 576];   // 2 x 9216 B
    __shared__ float  sreg[37];

    const int brow0 = blockIdx.x * (ROWS_PT * TILES);
    const bool hasB = (brow0 + ROWS_PT) < n;   // tile B = rows brow0+64..+127

    // ---- stage both tiles via DMA (latencies overlap), one drain ----
    {
        const int wid  = threadIdx.x >> 6;
        const int lane = threadIdx.x & 63;
        const float4* __restrict__ gA = reinterpret_cast<const float4*>(u + (size_t)brow0 * 36);
#pragma unroll
        for (int k = 0; k < 3; ++k) {
            const int base = k * 192 + wid * 64;   // f4 units, wave-uniform
            __builtin_amdgcn_global_load_lds(
                (const __attribute__((address_space(1))) void*)(gA + base + lane),
                (__attribute__((address_space(3))) void*)(s4 + base),
                16, 0, 0);
        }
        if (hasB) {
            const float4* __restrict__ gB = reinterpret_cast<const float4*>(u + (size_t)(brow0 + ROWS_PT) * 36);
#pragma unroll
            for (int k = 0; k < 3; ++k) {
                const int base = k * 192 + wid * 64;
                __builtin_amdgcn_global_load_lds(
                    (const __attribute__((address_space(1))) void*)(gB + base + lane),
                    (__attribute__((address_space(3))) void*)(s4 + 576 + base),
                    16, 0, 0);
            }
        }
    }
    if (threadIdx.x < 37) sreg[threadIdx.x] = reg[threadIdx.x];
    __syncthreads();   // drains vmcnt+lgkm once for both tiles

    const int rl = threadIdx.x / 3;          // row within tile, 0..63
    const int r  = threadIdx.x - 3 * rl;     // 0..2 -> output cols 12r..12r+11

    // ---- tile A ----
    seg_compute(s4, sreg, rl, r,
                w10, b10, w11, b11, w12, b12,
                w20, b20, w21, b21, w22, b22,
                w30, b30, w31, b31, w32, b32,
                reinterpret_cast<float4*>(out + (size_t)(brow0 + rl) * 36 + 12 * r));
    // ---- tile B ----
    if (hasB)
        seg_compute(s4 + 576, sreg, rl, r,
                    w10, b10, w11, b11, w12, b12,
                    w20, b20, w21, b21, w22, b22,
                    w30, b30, w31, b31, w32, b32,
                    reinterpret_cast<float4*>(out + (size_t)(brow0 + ROWS_PT + rl) * 36 + 12 * r));
}

extern "C" void kernel_launch(void* const* d_in, const int* in_sizes, int n_in,
                              void* d_out, int out_size, void* d_ws, size_t ws_size,
                              hipStream_t stream)
{
    const float* u   = (const float*)d_in[1];
    const float* reg = (const float*)d_in[2];
    const float* w10 = (const float*)d_in[3];
    const float* b10 = (const float*)d_in[4];
    const float* w11 = (const float*)d_in[5];
    const float* b11 = (const float*)d_in[6];
    const float* w12 = (const float*)d_in[7];
    const float* b12 = (const float*)d_in[8];
    const float* w20 = (const float*)d_in[9];
    const float* b20 = (const float*)d_in[10];
    const float* w21 = (const float*)d_in[11];
    const float* b21 = (const float*)d_in[12];
    const float* w22 = (const float*)d_in[13];
    const float* b22 = (const float*)d_in[14];
    const float* w30 = (const float*)d_in[15];
    const float* b30 = (const float*)d_in[16];
    const float* w31 = (const float*)d_in[17];
    const float* b31 = (const float*)d_in[18];
    const float* w32 = (const float*)d_in[19];
    const float* b32 = (const float*)d_in[20];
    float* out = (float*)d_out;

    const int n = in_sizes[1] / 36;                 // 1,000,000 rows (64 | n)
    const int rows_pb = ROWS_PT * TILES;            // 128
    const int grid = (n + rows_pb - 1) / rows_pb;   // 7813 blocks

    hipLaunchKernelGGL(mixmodel_kernel, dim3(grid), dim3(TPB), 0, stream,
                       u, reg, w10, b10, w11, b11, w12, b12,
                       w20, b20, w21, b21, w22, b22,
                       w30, b30, w31, b31, w32, b32, out, n);
}

// Round 12
// 86.764 us; speedup vs baseline: 1.0943x; 1.0943x over previous
//
#include <hip/hip_runtime.h>

// ---------------------------------------------------------------------------
// MixModel, wave-private LDS tiles — NO __syncthreads.
// Ladder: R1 136VGPR 127us | R2-R4 spill ~157 | R6 scalar 76us | R7 pk 74.8us
//   R8 2rows/thr 85 | R9 gridstride 94.8 | R10 block LDS-DMA tile 71.1us
//   R11 2 tiles/block 94.9us (codegen bloat: VALU cycles ~2x; block coupling)
// R12: each WAVE stages its own 64-row tile (9x global_load_lds dwordx4 into
//   wave-private LDS) and waits only on its own vmcnt(0) (+sched_barrier(0),
//   learn_hip rule #18). No cross-wave coupling at all: waves decorrelate,
//   drain stall ~40% -> ~13% of wave life. 64 lanes compute 192 segments in
//   3 passes (s=64p+lane, row=s/3, r=s%3); stores contiguous 48B/lane.
//   reg[] ds-written redundantly per wave (same values, benign race).
//   LDS 4*9216+148 ~= 37KB -> ~16 waves/CU (same cap as R10's measured 18).
// Spill signature: WRITE_SIZE >> 140,625 KB.
// ---------------------------------------------------------------------------

typedef float f2 __attribute__((ext_vector_type(2)));

__device__ __forceinline__ f2 splat2(float x) { f2 v; v.x = x; v.y = x; return v; }
__device__ __forceinline__ f2 mk2(float a, float b) { f2 v; v.x = a; v.y = b; return v; }
__device__ __forceinline__ f2 fma2(f2 a, f2 b, f2 c) { return __builtin_elementwise_fma(a, b, c); }
__device__ __forceinline__ f2 relu2(f2 a) { return __builtin_elementwise_max(a, splat2(0.0f)); }

// Packed MLP 3->3->6->3 for a pair of positions.
__device__ __forceinline__ void mlp_a2(f2 x0, f2 x1, f2 x2,
                                       const float* __restrict__ w0, const float* __restrict__ b0,
                                       const float* __restrict__ w1, const float* __restrict__ b1,
                                       const float* __restrict__ w2, const float* __restrict__ b2,
                                       f2& o0, f2& o1, f2& o2)
{
    f2 h0[3];
#pragma unroll
    for (int q = 0; q < 3; ++q) {
        f2 a = fma2(x0, splat2(w0[q*3+0]), splat2(b0[q]));
        a = fma2(x1, splat2(w0[q*3+1]), a);
        a = fma2(x2, splat2(w0[q*3+2]), a);
        h0[q] = relu2(a);
    }
    f2 h1[6];
#pragma unroll
    for (int q = 0; q < 6; ++q) {
        f2 a = fma2(h0[0], splat2(w1[q*3+0]), splat2(b1[q]));
        a = fma2(h0[1], splat2(w1[q*3+1]), a);
        a = fma2(h0[2], splat2(w1[q*3+2]), a);
        h1[q] = relu2(a);
    }
    f2 t[3];
#pragma unroll
    for (int q = 0; q < 3; ++q) {
        f2 a = fma2(h1[0], splat2(w2[q*6+0]), splat2(b2[q]));
#pragma unroll
        for (int i = 1; i < 6; ++i) a = fma2(h1[i], splat2(w2[q*6+i]), a);
        t[q] = a;
    }
    o0 = t[0]; o1 = t[1]; o2 = t[2];
}

// Packed MLP 4->4->6->2 for a pair of positions.
__device__ __forceinline__ void mlp_b2(f2 x0, f2 x1, f2 x2, f2 x3,
                                       const float* __restrict__ w0, const float* __restrict__ b0,
                                       const float* __restrict__ w1, const float* __restrict__ b1,
                                       const float* __restrict__ w2, const float* __restrict__ b2,
                                       f2& o0, f2& o1)
{
    f2 h0[4];
#pragma unroll
    for (int q = 0; q < 4; ++q) {
        f2 a = fma2(x0, splat2(w0[q*4+0]), splat2(b0[q]));
        a = fma2(x1, splat2(w0[q*4+1]), a);
        a = fma2(x2, splat2(w0[q*4+2]), a);
        a = fma2(x3, splat2(w0[q*4+3]), a);
        h0[q] = relu2(a);
    }
    f2 h1[6];
#pragma unroll
    for (int q = 0; q < 6; ++q) {
        f2 a = fma2(h0[0], splat2(w1[q*4+0]), splat2(b1[q]));
        a = fma2(h0[1], splat2(w1[q*4+1]), a);
        a = fma2(h0[2], splat2(w1[q*4+2]), a);
        a = fma2(h0[3], splat2(w1[q*4+3]), a);
        h1[q] = relu2(a);
    }
    f2 t[2];
#pragma unroll
    for (int q = 0; q < 2; ++q) {
        f2 a = fma2(h1[0], splat2(w2[q*6+0]), splat2(b2[q]));
#pragma unroll
        for (int i = 1; i < 6; ++i) a = fma2(h1[i], splat2(w2[q*6+i]), a);
        t[q] = a;
    }
    o0 = t[0]; o1 = t[1];
}

// One (row-in-tile, r) segment: window from LDS tile, compute, store 12 cols.
__device__ __forceinline__ void seg_compute(
    const float4* s4t, const float* sreg, int rl, int r,
    const float* __restrict__ w10, const float* __restrict__ b10,
    const float* __restrict__ w11, const float* __restrict__ b11,
    const float* __restrict__ w12, const float* __restrict__ b12,
    const float* __restrict__ w20, const float* __restrict__ b20,
    const float* __restrict__ w21, const float* __restrict__ b21,
    const float* __restrict__ w22, const float* __restrict__ b22,
    const float* __restrict__ w30, const float* __restrict__ b30,
    const float* __restrict__ w31, const float* __restrict__ b31,
    const float* __restrict__ w32, const float* __restrict__ b32,
    float4* __restrict__ o4)
{
    // ---- 20-col window: W(k) = u[row, (12r+k) mod 36], k=-4..15 ----
    float w_[20];
#pragma unroll
    for (int t = 0; t < 5; ++t) {
        int idx = 3 * r + 8 + t;               // 8..18
        if (idx >= 9) idx -= 9;                // 0..9
        if (idx >= 9) idx -= 9;                // 0..8 (double wrap)
        const float4 v = s4t[rl * 9 + idx];
        w_[4*t+0] = v.x; w_[4*t+1] = v.y; w_[4*t+2] = v.z; w_[4*t+3] = v.w;
    }
#define W(k) w_[(k) + 4]

    const f2 r02 = splat2(sreg[0]);
    const float* rb = sreg + 12 * r;

    f2 c0[2], c1[2], c2[2];   // pair P covers jj = 2P, 2P+1

#pragma unroll
    for (int P = 0; P < 2; ++P) {
        const int q = 6 * P;
        f2 a0, a1, a2;
        mlp_a2(mk2(W(q - 2), W(q + 1)), mk2(W(q), W(q + 3)), mk2(W(q + 1), W(q + 4)),
               w10, b10, w11, b11, w12, b12, a0, a1, a2);
        const f2 ua = mk2(W(q - 1), W(q + 2));
        const f2 ub = mk2(W(q + 2), W(q + 5));
        const f2 rv = mk2(rb[q + 1], rb[q + 4]);
        const f2 uv = mk2(W(q), W(q + 3));
        c0[P] = fma2(uv, rv, r02) + fma2(a2, ub, fma2(a1, ua, a0));
    }
#pragma unroll
    for (int P = 0; P < 2; ++P) {
        const int q = 6 * P;
        f2 a0, a1, a2;
        mlp_a2(mk2(W(q), W(q + 3)), mk2(W(q + 1), W(q + 4)), mk2(W(q + 3), W(q + 6)),
               w20, b20, w21, b21, w22, b22, a0, a1, a2);
        const f2 ua = mk2(W(q - 1), W(q + 2));
        const f2 ub = mk2(W(q + 2), W(q + 5));
        const f2 rv = mk2(rb[q + 2], rb[q + 5]);
        const f2 uv = mk2(W(q + 1), W(q + 4));
        c1[P] = fma2(uv, rv, r02) + fma2(a2, ub, fma2(a1, ua, a0));
    }
#pragma unroll
    for (int P = 0; P < 2; ++P) {
        const int q = 6 * P;
        f2 d0, d1;
        mlp_b2(mk2(W(q), W(q + 3)), mk2(W(q + 1), W(q + 4)),
               mk2(W(q + 3), W(q + 6)), mk2(W(q + 4), W(q + 7)),
               w30, b30, w31, b31, w32, b32, d0, d1);
        const f2 ub = mk2(W(q + 2), W(q + 5));
        const f2 rv = mk2(rb[q + 3], rb[q + 6]);
        c2[P] = fma2(ub, rv, r02) + fma2(d1, ub, d0);
    }
#undef W

    o4[0] = make_float4(c0[0].x, c1[0].x, c2[0].x, c0[0].y);
    o4[1] = make_float4(c1[0].y, c2[0].y, c0[1].x, c1[1].x);
    o4[2] = make_float4(c2[1].x, c0[1].y, c1[1].y, c2[1].y);
}

#define TPB 256           // 4 waves/block, each wave owns one 64-row tile

__global__ __launch_bounds__(TPB) void mixmodel_kernel(
    const float* __restrict__ u, const float* __restrict__ reg,
    const float* __restrict__ w10, const float* __restrict__ b10,
    const float* __restrict__ w11, const float* __restrict__ b11,
    const float* __restrict__ w12, const float* __restrict__ b12,
    const float* __restrict__ w20, const float* __restrict__ b20,
    const float* __restrict__ w21, const float* __restrict__ b21,
    const float* __restrict__ w22, const float* __restrict__ b22,
    const float* __restrict__ w30, const float* __restrict__ b30,
    const float* __restrict__ w31, const float* __restrict__ b31,
    const float* __restrict__ w32, const float* __restrict__ b32,
    float* __restrict__ out, int n)
{
    __shared__ float4 s4[4 * 576];       // 4 wave-private 9216-B tiles
    __shared__ float  sreg[37];          // written redundantly by each wave

    const int wv   = threadIdx.x >> 6;   // wave id in block, 0..3
    const int lane = threadIdx.x & 63;
    const int tile = blockIdx.x * 4 + wv;
    const int brow = tile * 64;          // 64 | n exactly (n = 1e6)
    if (brow >= n) return;               // whole-wave uniform exit

    float4* const s4t = s4 + wv * 576;   // this wave's tile

    // ---- stage this wave's 64-row tile: 9 x global_load_lds dwordx4 ----
    {
        const float4* __restrict__ g = reinterpret_cast<const float4*>(u) + (size_t)brow * 9;
#pragma unroll
        for (int k = 0; k < 9; ++k) {
            __builtin_amdgcn_global_load_lds(
                (const __attribute__((address_space(1))) void*)(g + k * 64 + lane),
                (__attribute__((address_space(3))) void*)(s4t + k * 64),
                16, 0, 0);
        }
    }
    // reg -> LDS (redundant per wave; identical values, benign)
    if (lane < 37) sreg[lane] = reg[lane];

    // wave-level drain only; no __syncthreads. Rule #18: fence the scheduler.
    asm volatile("s_waitcnt vmcnt(0) lgkmcnt(0)" ::: "memory");
    __builtin_amdgcn_sched_barrier(0);

    // ---- 3 passes x 64 lanes = 192 segments (64 rows x 3) ----
#pragma unroll
    for (int p = 0; p < 3; ++p) {
        const int s  = p * 64 + lane;
        const int rl = s / 3;            // magic-mul division
        const int r  = s - 3 * rl;
        seg_compute(s4t, sreg, rl, r,
                    w10, b10, w11, b11, w12, b12,
                    w20, b20, w21, b21, w22, b22,
                    w30, b30, w31, b31, w32, b32,
                    reinterpret_cast<float4*>(out + (size_t)(brow + rl) * 36 + 12 * r));
    }
}

extern "C" void kernel_launch(void* const* d_in, const int* in_sizes, int n_in,
                              void* d_out, int out_size, void* d_ws, size_t ws_size,
                              hipStream_t stream)
{
    const float* u   = (const float*)d_in[1];
    const float* reg = (const float*)d_in[2];
    const float* w10 = (const float*)d_in[3];
    const float* b10 = (const float*)d_in[4];
    const float* w11 = (const float*)d_in[5];
    const float* b11 = (const float*)d_in[6];
    const float* w12 = (const float*)d_in[7];
    const float* b12 = (const float*)d_in[8];
    const float* w20 = (const float*)d_in[9];
    const float* b20 = (const float*)d_in[10];
    const float* w21 = (const float*)d_in[11];
    const float* b21 = (const float*)d_in[12];
    const float* w22 = (const float*)d_in[13];
    const float* b22 = (const float*)d_in[14];
    const float* w30 = (const float*)d_in[15];
    const float* b30 = (const float*)d_in[16];
    const float* w31 = (const float*)d_in[17];
    const float* b31 = (const float*)d_in[18];
    const float* w32 = (const float*)d_in[19];
    const float* b32 = (const float*)d_in[20];
    float* out = (float*)d_out;

    const int n = in_sizes[1] / 36;            // 1,000,000 rows (64 | n)
    const int tiles = (n + 63) / 64;           // 15625
    const int grid  = (tiles + 3) / 4;         // 3907 blocks of 4 waves

    hipLaunchKernelGGL(mixmodel_kernel, dim3(grid), dim3(TPB), 0, stream,
                       u, reg, w10, b10, w11, b11, w12, b12,
                       w20, b20, w21, b21, w22, b22,
                       w30, b30, w31, b31, w32, b32, out, n);
}

// Round 13
// 75.657 us; speedup vs baseline: 1.2549x; 1.1468x over previous
//
#include <hip/hip_runtime.h>

// ---------------------------------------------------------------------------
// MixModel, 3 thread-segments/row, LDS-staged u-tile. R13 = R10 with 384-thr
// blocks (6 waves, 128 rows/tile) — everything else IDENTICAL to R10.
// Ladder: R1 136VGPR 127us | R2-R4 spill ~157 | R6 scalar 76us | R7 pk 74.8
//   R8 2rows/thr 85 | R9 gridstride 94.8 | R10 LDS-DMA 64-row tile 71.1us
//   R11 2tiles/block 94.9 (code bloat) | R12 wave-private 3-pass 86.8 (bloat)
// Lesson: R10's one-segment-per-thread body is the leanest codegen; R11/R12
//   died of fatter bodies, not of their pipelining ideas. Only block geometry
//   left: halve dispatch churn (15625 -> 7813 blocks, ~184 -> ~92 blocks/us)
//   without changing per-thread code at all.
// Spill signature: WRITE_SIZE >> 140,625 KB.
// ---------------------------------------------------------------------------

typedef float f2 __attribute__((ext_vector_type(2)));

__device__ __forceinline__ f2 splat2(float x) { f2 v; v.x = x; v.y = x; return v; }
__device__ __forceinline__ f2 mk2(float a, float b) { f2 v; v.x = a; v.y = b; return v; }
__device__ __forceinline__ f2 fma2(f2 a, f2 b, f2 c) { return __builtin_elementwise_fma(a, b, c); }
__device__ __forceinline__ f2 relu2(f2 a) { return __builtin_elementwise_max(a, splat2(0.0f)); }

// Packed MLP 3->3->6->3 for a pair of positions.
__device__ __forceinline__ void mlp_a2(f2 x0, f2 x1, f2 x2,
                                       const float* __restrict__ w0, const float* __restrict__ b0,
                                       const float* __restrict__ w1, const float* __restrict__ b1,
                                       const float* __restrict__ w2, const float* __restrict__ b2,
                                       f2& o0, f2& o1, f2& o2)
{
    f2 h0[3];
#pragma unroll
    for (int q = 0; q < 3; ++q) {
        f2 a = fma2(x0, splat2(w0[q*3+0]), splat2(b0[q]));
        a = fma2(x1, splat2(w0[q*3+1]), a);
        a = fma2(x2, splat2(w0[q*3+2]), a);
        h0[q] = relu2(a);
    }
    f2 h1[6];
#pragma unroll
    for (int q = 0; q < 6; ++q) {
        f2 a = fma2(h0[0], splat2(w1[q*3+0]), splat2(b1[q]));
        a = fma2(h0[1], splat2(w1[q*3+1]), a);
        a = fma2(h0[2], splat2(w1[q*3+2]), a);
        h1[q] = relu2(a);
    }
    f2 t[3];
#pragma unroll
    for (int q = 0; q < 3; ++q) {
        f2 a = fma2(h1[0], splat2(w2[q*6+0]), splat2(b2[q]));
#pragma unroll
        for (int i = 1; i < 6; ++i) a = fma2(h1[i], splat2(w2[q*6+i]), a);
        t[q] = a;
    }
    o0 = t[0]; o1 = t[1]; o2 = t[2];
}

// Packed MLP 4->4->6->2 for a pair of positions.
__device__ __forceinline__ void mlp_b2(f2 x0, f2 x1, f2 x2, f2 x3,
                                       const float* __restrict__ w0, const float* __restrict__ b0,
                                       const float* __restrict__ w1, const float* __restrict__ b1,
                                       const float* __restrict__ w2, const float* __restrict__ b2,
                                       f2& o0, f2& o1)
{
    f2 h0[4];
#pragma unroll
    for (int q = 0; q < 4; ++q) {
        f2 a = fma2(x0, splat2(w0[q*4+0]), splat2(b0[q]));
        a = fma2(x1, splat2(w0[q*4+1]), a);
        a = fma2(x2, splat2(w0[q*4+2]), a);
        a = fma2(x3, splat2(w0[q*4+3]), a);
        h0[q] = relu2(a);
    }
    f2 h1[6];
#pragma unroll
    for (int q = 0; q < 6; ++q) {
        f2 a = fma2(h0[0], splat2(w1[q*4+0]), splat2(b1[q]));
        a = fma2(h0[1], splat2(w1[q*4+1]), a);
        a = fma2(h0[2], splat2(w1[q*4+2]), a);
        a = fma2(h0[3], splat2(w1[q*4+3]), a);
        h1[q] = relu2(a);
    }
    f2 t[2];
#pragma unroll
    for (int q = 0; q < 2; ++q) {
        f2 a = fma2(h1[0], splat2(w2[q*6+0]), splat2(b2[q]));
#pragma unroll
        for (int i = 1; i < 6; ++i) a = fma2(h1[i], splat2(w2[q*6+i]), a);
        t[q] = a;
    }
    o0 = t[0]; o1 = t[1];
}

#define ROWS_PB 128
#define TPB 384   // 6 waves; ROWS_PB*9 f4 chunks = 1152 = 3*TPB

__global__ __launch_bounds__(TPB) void mixmodel_kernel(
    const float* __restrict__ u, const float* __restrict__ reg,
    const float* __restrict__ w10, const float* __restrict__ b10,
    const float* __restrict__ w11, const float* __restrict__ b11,
    const float* __restrict__ w12, const float* __restrict__ b12,
    const float* __restrict__ w20, const float* __restrict__ b20,
    const float* __restrict__ w21, const float* __restrict__ b21,
    const float* __restrict__ w22, const float* __restrict__ b22,
    const float* __restrict__ w30, const float* __restrict__ b30,
    const float* __restrict__ w31, const float* __restrict__ b31,
    const float* __restrict__ w32, const float* __restrict__ b32,
    float* __restrict__ out, int n)
{
    __shared__ float4 s4[ROWS_PB * 9];   // 18432 B u-tile
    __shared__ float  sreg[37];

    const int brow = blockIdx.x * ROWS_PB;

    // ---- stage 128-row u-tile via DMA: wave-uniform LDS base + lane*16 ----
    {
        const float4* __restrict__ g = reinterpret_cast<const float4*>(u + (size_t)brow * 36);
        const int wid  = threadIdx.x >> 6;
        const int lane = threadIdx.x & 63;
#pragma unroll
        for (int w = 0; w < 3; ++w) {
            const int base = w * TPB + wid * 64;   // f4 units, wave-uniform
            __builtin_amdgcn_global_load_lds(
                (const __attribute__((address_space(1))) void*)(g + base + lane),
                (__attribute__((address_space(3))) void*)(s4 + base),
                16, 0, 0);
        }
    }
    if (threadIdx.x < 37) sreg[threadIdx.x] = reg[threadIdx.x];
    asm volatile("s_waitcnt vmcnt(0)" ::: "memory");
    __syncthreads();

    const int rl = threadIdx.x / 3;          // row within tile, 0..127
    const int r  = threadIdx.x - 3 * rl;     // 0..2 -> output cols 12r..12r+11
    const int row = brow + rl;
    if (row >= n) return;

    // ---- 20-col window from LDS: W(k) = u[row, (12r+k) mod 36], k=-4..15 ----
    float w_[20];
#pragma unroll
    for (int t = 0; t < 5; ++t) {
        int idx = 3 * r + 8 + t;               // 8..18
        if (idx >= 9) idx -= 9;                // 0..9
        if (idx >= 9) idx -= 9;                // 0..8 (double wrap)
        const float4 v = s4[rl * 9 + idx];
        w_[4*t+0] = v.x; w_[4*t+1] = v.y; w_[4*t+2] = v.z; w_[4*t+3] = v.w;
    }
#define W(k) w_[(k) + 4]

    const f2 r02 = splat2(sreg[0]);
    const float* rb = sreg + 12 * r;          // LDS, broadcast reads

    f2 c0[2], c1[2], c2[2];   // pair P covers jj = 2P, 2P+1

    // ---- phase 1: MLP1 -> c0 ----
#pragma unroll
    for (int P = 0; P < 2; ++P) {
        const int q = 6 * P;
        f2 a0, a1, a2;
        mlp_a2(mk2(W(q - 2), W(q + 1)), mk2(W(q), W(q + 3)), mk2(W(q + 1), W(q + 4)),
               w10, b10, w11, b11, w12, b12, a0, a1, a2);
        const f2 ua = mk2(W(q - 1), W(q + 2));
        const f2 ub = mk2(W(q + 2), W(q + 5));
        const f2 rv = mk2(rb[q + 1], rb[q + 4]);
        const f2 uv = mk2(W(q), W(q + 3));
        c0[P] = fma2(uv, rv, r02) + fma2(a2, ub, fma2(a1, ua, a0));
    }
    // ---- phase 2: MLP2 -> c1 ----
#pragma unroll
    for (int P = 0; P < 2; ++P) {
        const int q = 6 * P;
        f2 a0, a1, a2;
        mlp_a2(mk2(W(q), W(q + 3)), mk2(W(q + 1), W(q + 4)), mk2(W(q + 3), W(q + 6)),
               w20, b20, w21, b21, w22, b22, a0, a1, a2);
        const f2 ua = mk2(W(q - 1), W(q + 2));
        const f2 ub = mk2(W(q + 2), W(q + 5));
        const f2 rv = mk2(rb[q + 2], rb[q + 5]);
        const f2 uv = mk2(W(q + 1), W(q + 4));
        c1[P] = fma2(uv, rv, r02) + fma2(a2, ub, fma2(a1, ua, a0));
    }
    // ---- phase 3: MLP3 -> c2 ----
#pragma unroll
    for (int P = 0; P < 2; ++P) {
        const int q = 6 * P;
        f2 d0, d1;
        mlp_b2(mk2(W(q), W(q + 3)), mk2(W(q + 1), W(q + 4)),
               mk2(W(q + 3), W(q + 6)), mk2(W(q + 4), W(q + 7)),
               w30, b30, w31, b31, w32, b32, d0, d1);
        const f2 ub = mk2(W(q + 2), W(q + 5));
        const f2 rv = mk2(rb[q + 3], rb[q + 6]);
        c2[P] = fma2(ub, rv, r02) + fma2(d1, ub, d0);
    }
#undef W

    // ---- store 12 contiguous cols at out[row, 12r..12r+11] ----
    float4* __restrict__ o4 = reinterpret_cast<float4*>(out + (size_t)row * 36 + 12 * r);
    o4[0] = make_float4(c0[0].x, c1[0].x, c2[0].x, c0[0].y);
    o4[1] = make_float4(c1[0].y, c2[0].y, c0[1].x, c1[1].x);
    o4[2] = make_float4(c2[1].x, c0[1].y, c1[1].y, c2[1].y);
}

extern "C" void kernel_launch(void* const* d_in, const int* in_sizes, int n_in,
                              void* d_out, int out_size, void* d_ws, size_t ws_size,
                              hipStream_t stream)
{
    const float* u   = (const float*)d_in[1];
    const float* reg = (const float*)d_in[2];
    const float* w10 = (const float*)d_in[3];
    const float* b10 = (const float*)d_in[4];
    const float* w11 = (const float*)d_in[5];
    const float* b11 = (const float*)d_in[6];
    const float* w12 = (const float*)d_in[7];
    const float* b12 = (const float*)d_in[8];
    const float* w20 = (const float*)d_in[9];
    const float* b20 = (const float*)d_in[10];
    const float* w21 = (const float*)d_in[11];
    const float* b21 = (const float*)d_in[12];
    const float* w22 = (const float*)d_in[13];
    const float* b22 = (const float*)d_in[14];
    const float* w30 = (const float*)d_in[15];
    const float* b30 = (const float*)d_in[16];
    const float* w31 = (const float*)d_in[17];
    const float* b31 = (const float*)d_in[18];
    const float* w32 = (const float*)d_in[19];
    const float* b32 = (const float*)d_in[20];
    float* out = (float*)d_out;

    const int n = in_sizes[1] / 36;            // 1,000,000 rows
    const int grid = (n + ROWS_PB - 1) / ROWS_PB;   // 7813 blocks

    hipLaunchKernelGGL(mixmodel_kernel, dim3(grid), dim3(TPB), 0, stream,
                       u, reg, w10, b10, w11, b11, w12, b12,
                       w20, b20, w21, b21, w22, b22,
                       w30, b30, w31, b31, w32, b32, out, n);
}